// Round 1
// 848.131 us; speedup vs baseline: 1.0430x; 1.0430x over previous
//
#include <hip/hip_runtime.h>
#include <cstdint>
#include <cstddef>

// Problem constants: B=32, T=4096, 2H=1024, DFF=512
#define B_SZ 32
#define T_SZ 4096
#define H2   1024
#define DFF_ 512
#define TM   64           // t-rows per block
#define CH_K 128          // K per chunk (4 MFMA steps of K=32)
#define NCHUNK 8          // 8 chunks * 128 = K=1024
#define NSTEP 32

typedef __attribute__((ext_vector_type(8))) short bf16x8;
typedef __attribute__((ext_vector_type(4))) float f32x4;

__device__ __forceinline__ unsigned short f2bf(float x) {
  unsigned u = __float_as_uint(x);
  u += 0x7fffu + ((u >> 16) & 1u);   // RNE
  return (unsigned short)(u >> 16);
}

// async HBM -> LDS, 16 B/lane, wave-uniform LDS base + lane*16
__device__ __forceinline__ void gll16(const float* g, void* l) {
  __builtin_amdgcn_global_load_lds(
      (const __attribute__((address_space(1))) unsigned int*)g,
      (__attribute__((address_space(3))) unsigned int*)l, 16, 0, 0);
}

// Pack U [512][1024] fp32 -> Upk in MFMA-fragment order:
// Upk[((ks*32 + ct)*64 + l)*8 + j] = bf16(U[ct*16 + (l&15)][ks*32 + (l>>4)*8 + j])
__global__ void prep_u_kernel(const float* __restrict__ U,
                              unsigned short* __restrict__ Upk) {
  int g = blockIdx.x * 256 + threadIdx.x;     // [0, 524288)
  int j  = g & 7;
  int l  = (g >> 3) & 63;
  int ct = (g >> 9) & 31;
  int ks = g >> 14;
  int f  = ct * 16 + (l & 15);
  int k  = ks * 32 + (l >> 4) * 8 + j;
  Upk[g] = f2bf(U[f * H2 + k]);
}

// ws[b][f] = s[b]·W[f] + Wb[f] + Ub[f]   (fp32, exact)
__global__ void prep_ws_kernel(const float* __restrict__ s, const float* __restrict__ W,
                               const float* __restrict__ Wb, const float* __restrict__ Ub,
                               float* __restrict__ wsm) {
  int idx = blockIdx.x * 256 + threadIdx.x;   // [0, 32*512)
  int b = idx >> 9, f = idx & 511;
  const float4* s4 = (const float4*)(s + b * 512);
  const float4* w4 = (const float4*)(W + f * 512);
  float acc = 0.f;
  #pragma unroll 4
  for (int i = 0; i < 128; ++i) {
    float4 a = s4[i], w = w4[i];
    acc += a.x * w.x + a.y * w.y + a.z * w.z + a.w * w.w;
  }
  wsm[idx] = acc + Wb[f] + Ub[f];
}

// Fused uh GEMM + tanh + energy + context.
// T3-style 2-phase async pipeline:
//   compute(chunk c from bf16 dbuf) || global_load_lds(chunk c+1 -> fp32 buf)
//   -> vmcnt(0)+barrier -> LDS convert fp32->bf16(RNE) -> barrier -> issue c+2.
// fp32 chunk layout: 32 slots of 1040 B (2 rows of 128 floats + 16 B pad);
// slot i holds rows {2i, 2i+1}; gll dest uniform per wave, lane stride 16 B.
__global__ __launch_bounds__(512, 4) void attn_main(
    const float* __restrict__ h, const unsigned short* __restrict__ Upk,
    const float* __restrict__ wsm, const float* __restrict__ Vw,
    const float* __restrict__ Vb, float* __restrict__ out) {
  __shared__ float F32c[8320];                 // 32 * 260 floats = 33280 B
  __shared__ unsigned short As16[2][4 * 2048]; // 2 x 16 KB bf16 fragment buffers
  __shared__ float ws_s[DFF_];
  __shared__ float V_s[DFF_];
  __shared__ float energy_part[8][TM];
  __shared__ float energy_s[TM];

  const int tid  = threadIdx.x;
  const int blk  = blockIdx.x;            // 2048 blocks
  const int b    = blk >> 6;
  const int t0   = (blk & 63) * TM;
  const int lane = tid & 63;
  const int cg   = tid >> 6;              // wave = col-group 0..7
  const int ln15 = lane & 15;
  const int q4   = lane >> 4;

  ws_s[tid] = wsm[b * DFF_ + tid];
  V_s[tid]  = Vw[tid];

  const float* hbase = h + ((size_t)(b * T_SZ + t0)) * H2;

  // staging: wave cg DMAs rows [8cg, 8cg+8) of the chunk; 4 slots/wave
  const float* gA = hbase + (size_t)(8 * cg + (lane >> 5)) * H2 + (lane & 31) * 4;
  char* lA = (char*)F32c + cg * (4 * 1040);

  // convert mapping: thread -> (row, 4-float quad), frag-order bf16 slot
  const int arow  = tid >> 3;             // 0..63
  const int acq   = tid & 7;              // k-quad within 32-col group
  const int rbyte = (arow >> 1) * 1040 + (arow & 1) * 512 + acq * 16;
  const int a_off = (arow >> 4) * 512 + (acq >> 1) * 128 + (arow & 15) * 8 + (acq & 1) * 4;

  const bf16x8* Upk8 = (const bf16x8*)Upk;  // fragment index = (ks*32+ct)*64 + lane

  f32x4 acc[16];
  #pragma unroll
  for (int i = 0; i < 16; ++i) acc[i] = (f32x4){0.f, 0.f, 0.f, 0.f};

  // ---- prologue: chunk0 DMA -> convert; chunk1 DMA in flight ----
  {
    const float* g0 = gA;
    gll16(g0,          lA);
    gll16(g0 + 2 * H2, lA + 1040);
    gll16(g0 + 4 * H2, lA + 2080);
    gll16(g0 + 6 * H2, lA + 3120);
  }
  asm volatile("s_waitcnt vmcnt(0)" ::: "memory");
  __syncthreads();
  {
    unsigned short* dst = &As16[0][0];
    #pragma unroll
    for (int j = 0; j < 4; ++j) {
      float4 v = *(const float4*)((const char*)F32c + rbyte + j * 128);
      ushort4 ab;
      ab.x = f2bf(v.x); ab.y = f2bf(v.y); ab.z = f2bf(v.z); ab.w = f2bf(v.w);
      *(ushort4*)&dst[j * 2048 + a_off] = ab;
    }
  }
  __syncthreads();
  {
    const float* g0 = gA + CH_K;
    gll16(g0,          lA);
    gll16(g0 + 2 * H2, lA + 1040);
    gll16(g0 + 4 * H2, lA + 2080);
    gll16(g0 + 6 * H2, lA + 3120);
  }

  bf16x8 bcur[4], bnxt[4];
  {
    int ub = (cg * 4) * 64 + lane;        // step 0 fragments
    #pragma unroll
    for (int i = 0; i < 4; ++i) bcur[i] = Upk8[ub + i * 64];
  }

  // ---- main pipeline: 8 chunks of 4 K-steps ----
  for (int c2 = 0; c2 < NCHUNK; ++c2) {
    const unsigned short* Ab = &As16[c2 & 1][0];
    #pragma unroll
    for (int sl = 0; sl < 4; ++sl) {
      // B depth-1 register prefetch (L2-hot Upk), continuous across chunks
      if (sl < 3 || c2 < NCHUNK - 1) {
        int sgn = c2 * 4 + sl + 1;
        int ub = (sgn * 32 + cg * 4) * 64 + lane;
        #pragma unroll
        for (int i = 0; i < 4; ++i) bnxt[i] = Upk8[ub + i * 64];
      }
      bf16x8 af[4];
      #pragma unroll
      for (int rt = 0; rt < 4; ++rt)
        af[rt] = *(const bf16x8*)&Ab[sl * 2048 + rt * 512 + lane * 8];
      #pragma unroll
      for (int ct2 = 0; ct2 < 4; ++ct2)
        #pragma unroll
        for (int rt = 0; rt < 4; ++rt)
          acc[ct2 * 4 + rt] =
            __builtin_amdgcn_mfma_f32_16x16x32_bf16(af[rt], bcur[ct2], acc[ct2 * 4 + rt], 0, 0, 0);
      #pragma unroll
      for (int i = 0; i < 4; ++i) bcur[i] = bnxt[i];
    }
    if (c2 < NCHUNK - 1) {
      // chunk c2+1 DMA has had the whole compute phase to land
      asm volatile("s_waitcnt vmcnt(0)" ::: "memory");
      __syncthreads();
      unsigned short* dst = &As16[(c2 + 1) & 1][0];
      #pragma unroll
      for (int j = 0; j < 4; ++j) {
        float4 v = *(const float4*)((const char*)F32c + rbyte + j * 128);
        ushort4 ab;
        ab.x = f2bf(v.x); ab.y = f2bf(v.y); ab.z = f2bf(v.z); ab.w = f2bf(v.w);
        *(ushort4*)&dst[j * 2048 + a_off] = ab;
      }
      __syncthreads();                    // F32c free + bf16 writes visible
      if (c2 < NCHUNK - 2) {
        const float* g0 = gA + (c2 + 2) * CH_K;
        gll16(g0,          lA);
        gll16(g0 + 2 * H2, lA + 1040);
        gll16(g0 + 4 * H2, lA + 2080);
        gll16(g0 + 6 * H2, lA + 3120);
      }
    }
  }

  // --- epilogue: x = tanh(ws + uh); energy partial = x·V ---
  // C/D layout: col f = tilebase + ln15, row = rt*16 + q4*4 + rg
  float esum[16];
  #pragma unroll
  for (int i = 0; i < 16; ++i) esum[i] = 0.f;
  #pragma unroll
  for (int ct2 = 0; ct2 < 4; ++ct2) {
    int f = cg * 64 + ct2 * 16 + ln15;
    float wsf = ws_s[f], vf = V_s[f];
    #pragma unroll
    for (int rt = 0; rt < 4; ++rt) {
      #pragma unroll
      for (int rg = 0; rg < 4; ++rg) {
        float z = wsf + acc[ct2 * 4 + rt][rg];
        float e = __expf(2.f * z);
        float x = 1.f - 2.f / (e + 1.f);
        esum[rt * 4 + rg] += x * vf;
      }
    }
  }
  #pragma unroll
  for (int i = 0; i < 16; ++i) {
    #pragma unroll
    for (int m = 1; m < 16; m <<= 1) esum[i] += __shfl_xor(esum[i], m, 64);
  }
  if (ln15 == 0) {
    #pragma unroll
    for (int rt = 0; rt < 4; ++rt)
      #pragma unroll
      for (int rg = 0; rg < 4; ++rg)
        energy_part[cg][rt * 16 + q4 * 4 + rg] = esum[rt * 4 + rg];
  }
  __syncthreads();
  if (tid < TM) {
    float e = Vb[0];
    #pragma unroll
    for (int w = 0; w < 8; ++w) e += energy_part[w][tid];
    energy_s[tid] = e;
  }
  __syncthreads();

  // --- context: out[b][e] += sum_row energy[row] * h[row][e] (L2-hot) ---
  int e0 = tid * 2;
  float c0 = 0.f, c1 = 0.f;
  const float2* h2p = (const float2*)hbase + (e0 >> 1);
  #pragma unroll 8
  for (int row = 0; row < TM; ++row) {
    float en = energy_s[row];
    float2 hv = h2p[(size_t)row * (H2 / 2)];
    c0 += en * hv.x;
    c1 += en * hv.y;
  }
  atomicAdd(&out[b * H2 + e0], c0);
  atomicAdd(&out[b * H2 + e0 + 1], c1);
}

extern "C" void kernel_launch(void* const* d_in, const int* in_sizes, int n_in,
                              void* d_out, int out_size, void* d_ws, size_t ws_size,
                              hipStream_t stream) {
  const float* s  = (const float*)d_in[0];
  const float* h  = (const float*)d_in[1];
  const float* Ww = (const float*)d_in[2];
  const float* Wb = (const float*)d_in[3];
  const float* Uw = (const float*)d_in[4];
  const float* Ub = (const float*)d_in[5];
  const float* Vw = (const float*)d_in[6];
  const float* Vb = (const float*)d_in[7];
  float* out = (float*)d_out;

  unsigned short* Upk = (unsigned short*)d_ws;                    // 1 MB
  float* wsm = (float*)((char*)d_ws + (size_t)NSTEP * 32768);     // 64 KB

  hipMemsetAsync(out, 0, (size_t)out_size * sizeof(float), stream);
  prep_u_kernel<<<(DFF_ * H2) / 256, 256, 0, stream>>>(Uw, Upk);
  prep_ws_kernel<<<(B_SZ * DFF_) / 256, 256, 0, stream>>>(s, Ww, Wb, Ub, wsm);
  attn_main<<<B_SZ * (T_SZ / TM), 512, 0, stream>>>(h, Upk, wsm, Vw, Vb, out);
}